// Round 3
// baseline (584.998 us; speedup 1.0000x reference)
//
#include <hip/hip_runtime.h>
#include <math.h>

namespace {

constexpr int N = 4, C = 96, H = 256, W = 256;
constexpr int HW = H * W;
constexpr int P1 = 128, P2 = 64, P3 = 32;
constexpr int CSPLIT = 2;            // channel chunks in gather kernel
constexpr float LMAX = 2.5f;         // MAX_NUM_LEVELS - 1

// ---------------------------------------------------------------- levels ----
__global__ __launch_bounds__(256) void levels_kernel(
    const float* __restrict__ grid, float* __restrict__ levels) {
  int idx = blockIdx.x * blockDim.x + threadIdx.x;
  if (idx >= N * H * W) return;
  int x = idx & (W - 1);
  int y = (idx >> 8) & (H - 1);
  int n = idx >> 16;
  const float* gb = grid + (size_t)n * H * W * 2;

  auto cget = [&](int yy, int xx, float& cx, float& cy) {
    yy = min(max(yy, 0), H - 1);
    xx = min(max(xx, 0), W - 1);
    const float* g = gb + ((size_t)yy * W + xx) * 2;
    cx = (float)(W - 1) * (g[0] + 1.0f) * 0.5f;
    cy = (float)(H - 1) * (g[1] + 1.0f) * 0.5f;
  };

  float cx, cy;
  cget(y, x, cx, cy);
  float m = 1.0f;  // clip(d^2, 1, inf) folded into init
  const int dxs[4] = {-1, 1, 0, 0};
  const int dys[4] = {0, 0, -1, 1};
#pragma unroll
  for (int i = 0; i < 4; i++) {
    float ox, oy;
    cget(y + dys[i], x + dxs[i], ox, oy);
    float dx = ox - cx, dy = oy - cy;
    m = fmaxf(m, dx * dx + dy * dy);
  }
  float lv = 0.5f * __log2f(m);  // log2(sqrt(max d^2))
  lv = fminf(fmaxf(lv, 0.0f), LMAX);
  levels[idx] = lv;
}

// ------------------------------------------------------------ downsample ----
// [1,3,3,1]/8 separable blur, reflect pad 1, stride 2.
__global__ __launch_bounds__(256) void downsample_kernel(
    const float* __restrict__ in, float* __restrict__ out, int NC, int Hi, int Wi) {
  int Ho = Hi >> 1, Wo = Wi >> 1;
  int idx = blockIdx.x * blockDim.x + threadIdx.x;
  int total = NC * Ho * Wo;
  if (idx >= total) return;
  int ow = idx % Wo;
  int t = idx / Wo;
  int oh = t % Ho;
  int nc = t / Ho;
  const float* p = in + (size_t)nc * Hi * Wi;

  const float fw[4] = {0.125f, 0.375f, 0.375f, 0.125f};
  int xs[4], ys[4];
#pragma unroll
  for (int k = 0; k < 4; k++) {
    int j = 2 * ow - 1 + k;
    if (j < 0) j = -j;
    if (j >= Wi) j = 2 * Wi - 2 - j;
    xs[k] = j;
    int r = 2 * oh - 1 + k;
    if (r < 0) r = -r;
    if (r >= Hi) r = 2 * Hi - 2 - r;
    ys[k] = r;
  }
  float acc = 0.0f;
#pragma unroll
  for (int a = 0; a < 4; a++) {
    const float* row = p + (size_t)ys[a] * Wi;
    float r = fmaf(fw[0], row[xs[0]],
              fmaf(fw[1], row[xs[1]],
              fmaf(fw[2], row[xs[2]], fw[3] * row[xs[3]])));
    acc = fmaf(fw[a], r, acc);
  }
  out[idx] = acc;
}

// ---------------------------------------------------------------- gather ----
// Collapsed separable weights for bilinear-sample(bilinear-upsample(level l)).
// Two 256-grid taps (q0 w=1-wq, q1 w=wq) each map to 2 small-grid taps at
// pos = (q+0.5)/2^l - 0.5 (half-pixel convention; clamp == jax edge renorm).
// Union covers <=3 consecutive small columns.
struct Axis { int i0, i1, i2; float w0, w1, w2; };

__device__ inline Axis axis_taps(int q0, int q1, float wq, int l, int S) {
  float inv = 1.0f / (float)(1 << l);
  float pos0 = ((float)q0 + 0.5f) * inv - 0.5f;
  float pos1 = ((float)q1 + 0.5f) * inv - 0.5f;
  int p0 = (int)floorf(pos0);
  int p1 = (int)floorf(pos1);
  float f0 = pos0 - (float)p0;
  float f1 = pos1 - (float)p1;
  int a0 = min(max(p0, 0), S - 1), a1 = min(max(p0 + 1, 0), S - 1);
  int b0 = min(max(p1, 0), S - 1), b1 = min(max(p1 + 1, 0), S - 1);
  int base = min(a0, b0);
  float w0 = 0.f, w1 = 0.f, w2 = 0.f;
  // static-select accumulation (avoid runtime-indexed array -> scratch)
  float v; int s;
  v = (1.0f - wq) * (1.0f - f0); s = a0 - base;
  w0 += (s == 0) ? v : 0.f; w1 += (s == 1) ? v : 0.f; w2 += (s == 2) ? v : 0.f;
  v = (1.0f - wq) * f0;          s = a1 - base;
  w0 += (s == 0) ? v : 0.f; w1 += (s == 1) ? v : 0.f; w2 += (s == 2) ? v : 0.f;
  v = wq * (1.0f - f1);          s = b0 - base;
  w0 += (s == 0) ? v : 0.f; w1 += (s == 1) ? v : 0.f; w2 += (s == 2) ? v : 0.f;
  v = wq * f1;                   s = b1 - base;
  w0 += (s == 0) ? v : 0.f; w1 += (s == 1) ? v : 0.f; w2 += (s == 2) ? v : 0.f;
  Axis r;
  r.i0 = base;
  r.i1 = min(base + 1, S - 1);
  r.i2 = min(base + 2, S - 1);
  r.w0 = w0; r.w1 = w1; r.w2 = w2;
  return r;
}

struct Taps { const float* p; int cs; int o[9]; float w[9]; };

__device__ inline Taps make_taps(int l, int n, int x0, int x1, float wx,
                                 int y0, int y1, float wy,
                                 const float* inputs, const float* pyr1,
                                 const float* pyr2, const float* pyr3) {
  int S = H >> l;
  const float* base = (l == 0) ? inputs : (l == 1) ? pyr1 : (l == 2) ? pyr2 : pyr3;
  int cs = S * S;
  Taps T;
  T.p = base + (size_t)n * C * cs;
  T.cs = cs;
  Axis ax = axis_taps(x0, x1, wx, l, S);
  Axis ay = axis_taps(y0, y1, wy, l, S);
  int r0 = ay.i0 * S, r1 = ay.i1 * S, r2 = ay.i2 * S;
  T.o[0] = r0 + ax.i0; T.o[1] = r0 + ax.i1; T.o[2] = r0 + ax.i2;
  T.o[3] = r1 + ax.i0; T.o[4] = r1 + ax.i1; T.o[5] = r1 + ax.i2;
  T.o[6] = r2 + ax.i0; T.o[7] = r2 + ax.i1; T.o[8] = r2 + ax.i2;
  T.w[0] = ay.w0 * ax.w0; T.w[1] = ay.w0 * ax.w1; T.w[2] = ay.w0 * ax.w2;
  T.w[3] = ay.w1 * ax.w0; T.w[4] = ay.w1 * ax.w1; T.w[5] = ay.w1 * ax.w2;
  T.w[6] = ay.w2 * ax.w0; T.w[7] = ay.w2 * ax.w1; T.w[8] = ay.w2 * ax.w2;
  return T;
}

__global__ __launch_bounds__(256) void gather_kernel(
    const float* __restrict__ inputs, const float* __restrict__ grid,
    const float* __restrict__ levels,
    const float* __restrict__ pyr1, const float* __restrict__ pyr2,
    const float* __restrict__ pyr3, float* __restrict__ out) {
  int idx = blockIdx.x * blockDim.x + threadIdx.x;
  if (idx >= N * H * W) return;
  int x = idx & (W - 1);
  int y = (idx >> 8) & (H - 1);
  int n = idx >> 16;

  float gx = grid[(size_t)idx * 2];
  float gy = grid[(size_t)idx * 2 + 1];
  // grid_sample, align_corners=False, border clamp
  float ix = fminf(fmaxf(fmaf(gx + 1.0f, (float)W * 0.5f, -0.5f), 0.0f), (float)(W - 1));
  float iy = fminf(fmaxf(fmaf(gy + 1.0f, (float)H * 0.5f, -0.5f), 0.0f), (float)(H - 1));
  int x0 = (int)floorf(ix); float wx = ix - (float)x0; int x1 = min(x0 + 1, W - 1);
  int y0 = (int)floorf(iy); float wy = iy - (float)y0; int y1 = min(y0 + 1, H - 1);

  float lv = levels[idx];
  float lf = floorf(lv);
  int l0 = (int)lf;
  float wl = lv - lf;
  int l1 = (wl > 0.f) ? (l0 + 1) : l0;

  Taps T0 = make_taps(l0, n, x0, x1, wx, y0, y1, wy, inputs, pyr1, pyr2, pyr3);
  Taps T1 = make_taps(l1, n, x0, x1, wx, y0, y1, wy, inputs, pyr1, pyr2, pyr3);

  constexpr int CC = C / CSPLIT;
  int cbeg = blockIdx.y * CC;
  const float* P0 = T0.p + (size_t)cbeg * T0.cs;
  const float* P1 = T1.p + (size_t)cbeg * T1.cs;
  float* po = out + (size_t)n * C * HW + (size_t)cbeg * HW + (size_t)y * W + x;

  for (int c = 0; c < CC; c++) {
    float v0 = 0.f, v1 = 0.f;
#pragma unroll
    for (int k = 0; k < 9; k++) v0 = fmaf(T0.w[k], P0[T0.o[k]], v0);
#pragma unroll
    for (int k = 0; k < 9; k++) v1 = fmaf(T1.w[k], P1[T1.o[k]], v1);
    *po = fmaf(wl, v1 - v0, v0);
    P0 += T0.cs;
    P1 += T1.cs;
    po += HW;
  }
}

}  // namespace

extern "C" void kernel_launch(void* const* d_in, const int* in_sizes, int n_in,
                              void* d_out, int out_size, void* d_ws, size_t ws_size,
                              hipStream_t stream) {
  const float* inputs = (const float*)d_in[0];
  const float* grid = (const float*)d_in[1];
  float* out = (float*)d_out;
  float* ws = (float*)d_ws;

  float* levels = ws;                               // N*H*W           = 1.0 MB
  float* pyr1 = levels + (size_t)N * H * W;         // N*C*128*128     = 25.2 MB
  float* pyr2 = pyr1 + (size_t)N * C * P1 * P1;     // N*C*64*64       =  6.3 MB
  float* pyr3 = pyr2 + (size_t)N * C * P2 * P2;     // N*C*32*32       =  1.6 MB

  int tpix = N * H * W;
  levels_kernel<<<(tpix + 255) / 256, 256, 0, stream>>>(grid, levels);

  int NC = N * C;
  int t1 = NC * P1 * P1;
  downsample_kernel<<<(t1 + 255) / 256, 256, 0, stream>>>(inputs, pyr1, NC, H, W);
  int t2 = NC * P2 * P2;
  downsample_kernel<<<(t2 + 255) / 256, 256, 0, stream>>>(pyr1, pyr2, NC, P1, P1);
  int t3 = NC * P3 * P3;
  downsample_kernel<<<(t3 + 255) / 256, 256, 0, stream>>>(pyr2, pyr3, NC, P2, P2);

  dim3 gg((tpix + 255) / 256, CSPLIT);
  gather_kernel<<<gg, 256, 0, stream>>>(inputs, grid, levels, pyr1, pyr2, pyr3, out);
}

// Round 4
// 398.109 us; speedup vs baseline: 1.4694x; 1.4694x over previous
//
#include <hip/hip_runtime.h>
#include <math.h>

namespace {

constexpr int N = 4, C = 96, H = 256, W = 256;
constexpr int HW = H * W;
constexpr int P1 = 128, P2 = 64, P3 = 32;
constexpr int CSPLIT = 2;            // channel chunks in gather kernel
constexpr float LMAX = 2.5f;         // MAX_NUM_LEVELS - 1

typedef float v4 __attribute__((ext_vector_type(4)));
// force 4-byte alignment so compiler emits unaligned global_load_dwordx4
struct __attribute__((packed, aligned(4))) V4U { v4 v; };

__device__ inline v4 load4u(const float* p) {
  return reinterpret_cast<const V4U*>(p)->v;
}
__device__ inline float dot4(v4 a, v4 w) {
  return fmaf(a.x, w.x, fmaf(a.y, w.y, fmaf(a.z, w.z, a.w * w.w)));
}

// ---------------------------------------------------------------- levels ----
__global__ __launch_bounds__(256) void levels_kernel(
    const float* __restrict__ grid, float* __restrict__ levels) {
  int idx = blockIdx.x * 256 + threadIdx.x;   // grid sized exactly
  int x = idx & (W - 1);
  int y = (idx >> 8) & (H - 1);
  int n = idx >> 16;
  const float2* gb = reinterpret_cast<const float2*>(grid) + (size_t)n * HW;

  auto cget = [&](int yy, int xx, float& cx, float& cy) {
    yy = min(max(yy, 0), H - 1);
    xx = min(max(xx, 0), W - 1);
    float2 g = gb[yy * W + xx];
    cx = (float)(W - 1) * (g.x + 1.0f) * 0.5f;
    cy = (float)(H - 1) * (g.y + 1.0f) * 0.5f;
  };

  float cx, cy;
  cget(y, x, cx, cy);
  float m = 1.0f;  // clip(d^2, 1, inf) folded into init
  const int dxs[4] = {-1, 1, 0, 0};
  const int dys[4] = {0, 0, -1, 1};
#pragma unroll
  for (int i = 0; i < 4; i++) {
    float ox, oy;
    cget(y + dys[i], x + dxs[i], ox, oy);
    float dx = ox - cx, dy = oy - cy;
    m = fmaxf(m, dx * dx + dy * dy);
  }
  float lv = 0.5f * __log2f(m);  // log2(sqrt(max d^2))
  lv = fminf(fmaxf(lv, 0.0f), LMAX);
  levels[idx] = lv;
}

// ------------------------------------------------------------ downsample ----
// [1,3,3,1]/8 separable blur, reflect pad 1, stride 2. 4x float4 row loads.
__global__ __launch_bounds__(256) void downsample_kernel(
    const float* __restrict__ in, float* __restrict__ out,
    int Hi, int Wi, int lw, int lh) {
  int idx = blockIdx.x * 256 + threadIdx.x;   // grid sized exactly (pow2)
  int Wo = Wi >> 1, Ho = Hi >> 1;
  int ow = idx & (Wo - 1);
  int oh = (idx >> lw) & (Ho - 1);
  int nc = idx >> (lw + lh);
  const float* p = in + (size_t)nc * Hi * Wi;

  // x: one 4-wide window [wsx..wsx+3]; 3 cases fold the reflect
  int wsx;
  v4 wx;
  if (ow == 0)            { wsx = 0;      wx = (v4){0.375f, 0.5f, 0.125f, 0.0f}; }
  else if (ow == Wo - 1)  { wsx = Wi - 4; wx = (v4){0.0f, 0.125f, 0.5f, 0.375f}; }
  else                    { wsx = 2 * ow - 1; wx = (v4){0.125f, 0.375f, 0.375f, 0.125f}; }

  const float fw[4] = {0.125f, 0.375f, 0.375f, 0.125f};
  int ys[4];
#pragma unroll
  for (int k = 0; k < 4; k++) {
    int r = 2 * oh - 1 + k;
    if (r < 0) r = -r;
    if (r >= Hi) r = 2 * Hi - 2 - r;
    ys[k] = r;
  }
  float acc = 0.0f;
#pragma unroll
  for (int a = 0; a < 4; a++) {
    v4 t = load4u(p + (size_t)ys[a] * Wi + wsx);
    acc = fmaf(fw[a], dot4(t, wx), acc);
  }
  out[idx] = acc;
}

// ---------------------------------------------------------------- gather ----
// Collapsed separable weights for bilinear-sample(bilinear-upsample(level l)).
// x-axis: all <=3 taps fall in window [ws..ws+3], ws=min(a0,S-4) -> one
// unaligned float4 load per row. y-axis: 3 clamped row indices.
struct LTaps {
  const float* p; int cs;
  int o0, o1, o2;          // row byte offsets (in floats): row*S + ws
  v4 wx;
  float wy0, wy1, wy2;
};

__device__ inline void axis_x(int q0, int q1, float wq, int l, int S,
                              int& ws, v4& w) {
  float inv = 1.0f / (float)(1 << l);
  float pos0 = ((float)q0 + 0.5f) * inv - 0.5f;
  float pos1 = ((float)q1 + 0.5f) * inv - 0.5f;
  int p0 = (int)floorf(pos0), p1 = (int)floorf(pos1);
  float f0 = pos0 - (float)p0, f1 = pos1 - (float)p1;
  int a0 = min(max(p0, 0), S - 1), a1 = min(max(p0 + 1, 0), S - 1);
  int b0 = min(max(p1, 0), S - 1), b1 = min(max(p1 + 1, 0), S - 1);
  ws = min(a0, S - 4);  // a0 = min tap (p1>=p0 => b0>=a0); window holds all taps
  float w0 = 0.f, w1 = 0.f, w2 = 0.f, w3 = 0.f;
  float v; int s;
  v = (1.0f - wq) * (1.0f - f0); s = a0 - ws;
  w0 += (s == 0) ? v : 0.f; w1 += (s == 1) ? v : 0.f; w2 += (s == 2) ? v : 0.f; w3 += (s == 3) ? v : 0.f;
  v = (1.0f - wq) * f0;          s = a1 - ws;
  w0 += (s == 0) ? v : 0.f; w1 += (s == 1) ? v : 0.f; w2 += (s == 2) ? v : 0.f; w3 += (s == 3) ? v : 0.f;
  v = wq * (1.0f - f1);          s = b0 - ws;
  w0 += (s == 0) ? v : 0.f; w1 += (s == 1) ? v : 0.f; w2 += (s == 2) ? v : 0.f; w3 += (s == 3) ? v : 0.f;
  v = wq * f1;                   s = b1 - ws;
  w0 += (s == 0) ? v : 0.f; w1 += (s == 1) ? v : 0.f; w2 += (s == 2) ? v : 0.f; w3 += (s == 3) ? v : 0.f;
  w = (v4){w0, w1, w2, w3};
}

__device__ inline void axis_y(int q0, int q1, float wq, int l, int S,
                              int& i0, int& i1, int& i2,
                              float& w0, float& w1, float& w2) {
  float inv = 1.0f / (float)(1 << l);
  float pos0 = ((float)q0 + 0.5f) * inv - 0.5f;
  float pos1 = ((float)q1 + 0.5f) * inv - 0.5f;
  int p0 = (int)floorf(pos0), p1 = (int)floorf(pos1);
  float f0 = pos0 - (float)p0, f1 = pos1 - (float)p1;
  int a0 = min(max(p0, 0), S - 1), a1 = min(max(p0 + 1, 0), S - 1);
  int b0 = min(max(p1, 0), S - 1), b1 = min(max(p1 + 1, 0), S - 1);
  int base = min(a0, b0);
  w0 = 0.f; w1 = 0.f; w2 = 0.f;
  float v; int s;
  v = (1.0f - wq) * (1.0f - f0); s = a0 - base;
  w0 += (s == 0) ? v : 0.f; w1 += (s == 1) ? v : 0.f; w2 += (s == 2) ? v : 0.f;
  v = (1.0f - wq) * f0;          s = a1 - base;
  w0 += (s == 0) ? v : 0.f; w1 += (s == 1) ? v : 0.f; w2 += (s == 2) ? v : 0.f;
  v = wq * (1.0f - f1);          s = b0 - base;
  w0 += (s == 0) ? v : 0.f; w1 += (s == 1) ? v : 0.f; w2 += (s == 2) ? v : 0.f;
  v = wq * f1;                   s = b1 - base;
  w0 += (s == 0) ? v : 0.f; w1 += (s == 1) ? v : 0.f; w2 += (s == 2) ? v : 0.f;
  i0 = base;
  i1 = min(base + 1, S - 1);
  i2 = min(base + 2, S - 1);
}

__device__ inline LTaps make_taps(int l, int n, int x0, int x1, float wx,
                                  int y0, int y1, float wy,
                                  const float* inputs, const float* pyr1,
                                  const float* pyr2, const float* pyr3) {
  int S = H >> l;
  const float* base = (l == 0) ? inputs : (l == 1) ? pyr1 : (l == 2) ? pyr2 : pyr3;
  int cs = S * S;
  LTaps T;
  T.p = base + (size_t)n * C * cs;
  T.cs = cs;
  int ws; v4 wxv;
  axis_x(x0, x1, wx, l, S, ws, wxv);
  int r0, r1, r2;
  axis_y(y0, y1, wy, l, S, r0, r1, r2, T.wy0, T.wy1, T.wy2);
  T.o0 = r0 * S + ws;
  T.o1 = r1 * S + ws;
  T.o2 = r2 * S + ws;
  T.wx = wxv;
  return T;
}

__global__ __launch_bounds__(256) void gather_kernel(
    const float* __restrict__ inputs, const float* __restrict__ grid,
    const float* __restrict__ levels,
    const float* __restrict__ pyr1, const float* __restrict__ pyr2,
    const float* __restrict__ pyr3, float* __restrict__ out) {
  int idx = blockIdx.x * 256 + threadIdx.x;   // grid sized exactly
  int x = idx & (W - 1);
  int y = (idx >> 8) & (H - 1);
  int n = idx >> 16;

  float2 g = reinterpret_cast<const float2*>(grid)[idx];
  // grid_sample, align_corners=False, border clamp
  float ix = fminf(fmaxf(fmaf(g.x + 1.0f, (float)W * 0.5f, -0.5f), 0.0f), (float)(W - 1));
  float iy = fminf(fmaxf(fmaf(g.y + 1.0f, (float)H * 0.5f, -0.5f), 0.0f), (float)(H - 1));
  int x0 = (int)floorf(ix); float wx = ix - (float)x0; int x1 = min(x0 + 1, W - 1);
  int y0 = (int)floorf(iy); float wy = iy - (float)y0; int y1 = min(y0 + 1, H - 1);

  float lv = levels[idx];
  float lf = floorf(lv);
  int l0 = (int)lf;
  float wl = lv - lf;
  int l1 = (wl > 0.f) ? (l0 + 1) : l0;

  LTaps T0 = make_taps(l0, n, x0, x1, wx, y0, y1, wy, inputs, pyr1, pyr2, pyr3);
  LTaps T1 = make_taps(l1, n, x0, x1, wx, y0, y1, wy, inputs, pyr1, pyr2, pyr3);

  constexpr int CC = C / CSPLIT;
  int cbeg = blockIdx.y * CC;
  const float* P0 = T0.p + (size_t)cbeg * T0.cs;
  const float* P1 = T1.p + (size_t)cbeg * T1.cs;
  float* po = out + (size_t)n * C * HW + (size_t)cbeg * HW + (size_t)y * W + x;

#pragma unroll 2
  for (int c = 0; c < CC; c++) {
    // issue all 6 loads first (independent -> overlap latency)
    v4 a0 = load4u(P0 + T0.o0);
    v4 a1 = load4u(P0 + T0.o1);
    v4 a2 = load4u(P0 + T0.o2);
    v4 b0 = load4u(P1 + T1.o0);
    v4 b1 = load4u(P1 + T1.o1);
    v4 b2 = load4u(P1 + T1.o2);
    float v0 = T0.wy0 * dot4(a0, T0.wx);
    v0 = fmaf(T0.wy1, dot4(a1, T0.wx), v0);
    v0 = fmaf(T0.wy2, dot4(a2, T0.wx), v0);
    float v1 = T1.wy0 * dot4(b0, T1.wx);
    v1 = fmaf(T1.wy1, dot4(b1, T1.wx), v1);
    v1 = fmaf(T1.wy2, dot4(b2, T1.wx), v1);
    *po = fmaf(wl, v1 - v0, v0);
    P0 += T0.cs;
    P1 += T1.cs;
    po += HW;
  }
}

}  // namespace

extern "C" void kernel_launch(void* const* d_in, const int* in_sizes, int n_in,
                              void* d_out, int out_size, void* d_ws, size_t ws_size,
                              hipStream_t stream) {
  const float* inputs = (const float*)d_in[0];
  const float* grid = (const float*)d_in[1];
  float* out = (float*)d_out;
  float* ws = (float*)d_ws;

  float* levels = ws;                               // N*H*W           = 1.0 MB
  float* pyr1 = levels + (size_t)N * H * W;         // N*C*128*128     = 25.2 MB
  float* pyr2 = pyr1 + (size_t)N * C * P1 * P1;     // N*C*64*64       =  6.3 MB
  float* pyr3 = pyr2 + (size_t)N * C * P2 * P2;     // N*C*32*32       =  1.6 MB

  int tpix = N * H * W;
  levels_kernel<<<tpix / 256, 256, 0, stream>>>(grid, levels);

  int NC = N * C;
  downsample_kernel<<<(NC * P1 * P1) / 256, 256, 0, stream>>>(inputs, pyr1, H, W, 7, 7);
  downsample_kernel<<<(NC * P2 * P2) / 256, 256, 0, stream>>>(pyr1, pyr2, P1, P1, 6, 6);
  downsample_kernel<<<(NC * P3 * P3) / 256, 256, 0, stream>>>(pyr2, pyr3, P2, P2, 5, 5);

  dim3 gg(tpix / 256, CSPLIT);
  gather_kernel<<<gg, 256, 0, stream>>>(inputs, grid, levels, pyr1, pyr2, pyr3, out);
}

// Round 5
// 259.695 us; speedup vs baseline: 2.2526x; 1.5330x over previous
//
#include <hip/hip_runtime.h>
#include <math.h>

namespace {

constexpr int N = 4, C = 96, H = 256, W = 256;
constexpr int HW = H * W;
constexpr float LMAX = 2.5f;

typedef float v4 __attribute__((ext_vector_type(4)));
struct __attribute__((packed, aligned(4))) V4U { v4 v; };
__device__ inline v4 load4u(const float* p) {
  return reinterpret_cast<const V4U*>(p)->v;
}

// ---------------------------------------------------------------- levels ----
__global__ __launch_bounds__(256) void levels_kernel(
    const float* __restrict__ grid, float* __restrict__ levels) {
  int idx = blockIdx.x * 256 + threadIdx.x;
  int x = idx & (W - 1);
  int y = (idx >> 8) & (H - 1);
  int n = idx >> 16;
  const float2* gb = reinterpret_cast<const float2*>(grid) + (size_t)n * HW;

  auto cget = [&](int yy, int xx, float& cx, float& cy) {
    yy = min(max(yy, 0), H - 1);
    xx = min(max(xx, 0), W - 1);
    float2 g = gb[yy * W + xx];
    cx = (float)(W - 1) * (g.x + 1.0f) * 0.5f;
    cy = (float)(H - 1) * (g.y + 1.0f) * 0.5f;
  };

  float cx, cy;
  cget(y, x, cx, cy);
  float m = 1.0f;
  const int dxs[4] = {-1, 1, 0, 0};
  const int dys[4] = {0, 0, -1, 1};
#pragma unroll
  for (int i = 0; i < 4; i++) {
    float ox, oy;
    cget(y + dys[i], x + dxs[i], ox, oy);
    float dx = ox - cx, dy = oy - cy;
    m = fmaxf(m, dx * dx + dy * dy);
  }
  float lv = 0.5f * __log2f(m);
  lv = fminf(fmaxf(lv, 0.0f), LMAX);
  levels[idx] = lv;
}

// ------------------------------------------------- tiled downsample ---------
// [1,3,3,1]/8 blur, reflect pad 1, stride 2. 32x32 output tile per block;
// stage 68x68 input region (reflect applied at staging) in LDS.
__global__ __launch_bounds__(256) void downsample_tiled(
    const float* __restrict__ in, float* __restrict__ out, int Wi, int T) {
  __shared__ float s[68 * 68];
  int Wo = Wi >> 1;
  int tile = blockIdx.x;
  int nc = blockIdx.y;
  int tx0 = (tile % T) * 32, ty0 = (tile / T) * 32;
  int ix0 = 2 * tx0 - 2, iy0 = 2 * ty0 - 2;
  const float* p = in + (size_t)nc * Wi * Wi;
  int tid = threadIdx.x;

  for (int k = 0; k < 19; k++) {
    int e = tid + 256 * k;
    if (e < 68 * 68) {
      int yy = e / 68, xx = e - 68 * yy;
      int gy = iy0 + yy; gy = gy < 0 ? -gy : (gy >= Wi ? 2 * Wi - 2 - gy : gy);
      int gx = ix0 + xx; gx = gx < 0 ? -gx : (gx >= Wi ? 2 * Wi - 2 - gx : gx);
      s[e] = p[(size_t)gy * Wi + gx];
    }
  }
  __syncthreads();

  const float fw[4] = {0.125f, 0.375f, 0.375f, 0.125f};
  int dx = tid & 31, dy0 = tid >> 5;
  float* po = out + (size_t)nc * Wo * Wo;
#pragma unroll
  for (int r = 0; r < 4; r++) {
    int dy = dy0 + 8 * r;
    float acc = 0.0f;
#pragma unroll
    for (int a = 0; a < 4; a++) {
      // abs tap row = 2*oy-1+a -> rel = 2*dy+1+a; col rel = 2*dx+1+k
      const float* row = s + (2 * dy + 1 + a) * 68 + 2 * dx + 1;
      float rsum = fmaf(fw[0], row[0],
                   fmaf(fw[1], row[1],
                   fmaf(fw[2], row[2], fw[3] * row[3])));
      acc = fmaf(fw[a], rsum, acc);
    }
    po[(size_t)(ty0 + dy) * Wo + tx0 + dx] = acc;
  }
}

// ---------------------------------------------------------------- gather ----
// abs tap indices + weights for one axis at level l (verbatim math from the
// passing round-3/4 kernels).
__device__ inline void axis3(int q0, int q1, float wq, int l, int S,
                             int* ii, float* ww) {
  float inv = 1.0f / (float)(1 << l);
  float pos0 = ((float)q0 + 0.5f) * inv - 0.5f;
  float pos1 = ((float)q1 + 0.5f) * inv - 0.5f;
  int p0 = (int)floorf(pos0), p1 = (int)floorf(pos1);
  float f0 = pos0 - (float)p0, f1 = pos1 - (float)p1;
  int a0 = min(max(p0, 0), S - 1), a1 = min(max(p0 + 1, 0), S - 1);
  int b0 = min(max(p1, 0), S - 1), b1 = min(max(p1 + 1, 0), S - 1);
  int base = min(a0, b0);
  float w0 = 0.f, w1 = 0.f, w2 = 0.f;
  float v; int s;
  v = (1.0f - wq) * (1.0f - f0); s = a0 - base;
  w0 += (s == 0) ? v : 0.f; w1 += (s == 1) ? v : 0.f; w2 += (s == 2) ? v : 0.f;
  v = (1.0f - wq) * f0;          s = a1 - base;
  w0 += (s == 0) ? v : 0.f; w1 += (s == 1) ? v : 0.f; w2 += (s == 2) ? v : 0.f;
  v = wq * (1.0f - f1);          s = b0 - base;
  w0 += (s == 0) ? v : 0.f; w1 += (s == 1) ? v : 0.f; w2 += (s == 2) ? v : 0.f;
  v = wq * f1;                   s = b1 - base;
  w0 += (s == 0) ? v : 0.f; w1 += (s == 1) ? v : 0.f; w2 += (s == 2) ? v : 0.f;
  ii[0] = base;
  ii[1] = min(base + 1, S - 1);
  ii[2] = min(base + 2, S - 1);
  ww[0] = w0; ww[1] = w1; ww[2] = w2;
}

// LDS: quad-planar per level: dword = OFF + q*SZ*4 + tf*4 + j  (c = 4q+j)
// L1: SZ=256 (16x16) @0 ; L2: SZ=100 (10x10) @8192 ; L3: SZ=36 (6x6) @11392
constexpr int L2OFF = 8192, L3OFF = 11392, LDSTOT = 12544;

__global__ __launch_bounds__(256, 3) void gather_tiled(
    const float* __restrict__ inputs, const float* __restrict__ grid,
    const float* __restrict__ levels, const float* __restrict__ pyr1,
    const float* __restrict__ pyr2, const float* __restrict__ pyr3,
    float* __restrict__ out) {
  __shared__ __align__(16) float lds[LDSTOT];
  int tile = blockIdx.x, g = blockIdx.y, n = blockIdx.z;
  int tx0 = (tile & 15) << 4, ty0 = (tile >> 4) << 4;
  int gb = g * 32;
  int tid = threadIdx.x;

  // early per-pixel loads (overlap with staging)
  int px = tid & 15, py = tid >> 4;
  int x = tx0 + px, y = ty0 + py;
  int pidx = n * HW + y * W + x;
  float2 gxy = reinterpret_cast<const float2*>(grid)[pidx];
  float lv = levels[pidx];

  // staged-region origins (proof: queries q in [tx0-7, tx0+22])
  int rsx1 = min(max((tx0 >> 1) - 4, 0), 128 - 16);
  int rsy1 = min(max((ty0 >> 1) - 4, 0), 128 - 16);
  int rsx2 = min(max((tx0 >> 2) - 3, 0), 64 - 10);
  int rsy2 = min(max((ty0 >> 2) - 3, 0), 64 - 10);
  int rsx3 = min(max((tx0 >> 3) - 2, 0), 32 - 6);
  int rsy3 = min(max((ty0 >> 3) - 2, 0), 32 - 6);

  // ---- stage L1: 32ch x 256 taps (scalar, coalesced) ----
  {
    const float* base = pyr1 + ((size_t)(n * C + gb)) * (128 * 128);
#pragma unroll
    for (int k = 0; k < 32; k++) {
      int e = tid + 256 * k;           // = c*256 + tf
      int c = e >> 8, tf = e & 255;
      int yy = tf >> 4, xx = tf & 15;
      float t = base[(size_t)c * (128 * 128) + (rsy1 + yy) * 128 + rsx1 + xx];
      lds[(c >> 2) * 1024 + tf * 4 + (c & 3)] = t;
    }
  }
  // ---- stage L2: 32ch x 100 taps ----
  {
    const float* base = pyr2 + ((size_t)(n * C + gb)) * (64 * 64);
    for (int k = 0; k < 13; k++) {
      int e = tid + 256 * k;
      if (e < 3200) {
        int c = e / 100, tf = e - 100 * c;
        int yy = tf / 10, xx = tf - 10 * yy;
        float t = base[(size_t)c * (64 * 64) + (rsy2 + yy) * 64 + rsx2 + xx];
        lds[L2OFF + (c >> 2) * 400 + tf * 4 + (c & 3)] = t;
      }
    }
  }
  // ---- stage L3: 32ch x 36 taps ----
  {
    const float* base = pyr3 + ((size_t)(n * C + gb)) * (32 * 32);
    for (int k = 0; k < 5; k++) {
      int e = tid + 256 * k;
      if (e < 1152) {
        int c = e / 36, tf = e - 36 * c;
        int yy = tf / 6, xx = tf - 6 * yy;
        float t = base[(size_t)c * (32 * 32) + (rsy3 + yy) * 32 + rsx3 + xx];
        lds[L3OFF + (c >> 2) * 144 + tf * 4 + (c & 3)] = t;
      }
    }
  }
  __syncthreads();

  // sampling coords (grid_sample border, align_corners=False)
  float ix = fminf(fmaxf(fmaf(gxy.x + 1.0f, 128.0f, -0.5f), 0.0f), 255.0f);
  float iy = fminf(fmaxf(fmaf(gxy.y + 1.0f, 128.0f, -0.5f), 0.0f), 255.0f);
  int x0 = (int)floorf(ix); float wx = ix - (float)x0; int x1 = min(x0 + 1, 255);
  int y0 = (int)floorf(iy); float wy = iy - (float)y0; int y1 = min(y0 + 1, 255);

  float lf = floorf(lv);
  int l0 = (int)lf;
  float wl = lv - lf;
  int lB = l0 + 1;  // always in [1,3]; wl==0 makes B's value irrelevant

  auto meta = [&](int l, int& off, int& sz, int& rw, int& rx, int& ry, int& S) {
    if (l == 1)      { off = 0;     sz = 256; rw = 16; rx = rsx1; ry = rsy1; S = 128; }
    else if (l == 2) { off = L2OFF; sz = 100; rw = 10; rx = rsx2; ry = rsy2; S = 64; }
    else             { off = L3OFF; sz = 36;  rw = 6;  rx = rsx3; ry = rsy3; S = 32; }
  };

  // B-level taps (always LDS)
  int offB, szB, rwB, rxB, ryB, SB;
  meta(lB, offB, szB, rwB, rxB, ryB, SB);
  int tfB[9]; float wB[9];
  {
    int xi[3]; float xw[3]; axis3(x0, x1, wx, lB, SB, xi, xw);
    int yi[3]; float yw[3]; axis3(y0, y1, wy, lB, SB, yi, yw);
#pragma unroll
    for (int r = 0; r < 3; r++)
#pragma unroll
      for (int cc = 0; cc < 3; cc++) {
        int ry_ = min(max(yi[r] - ryB, 0), rwB - 1);
        int rx_ = min(max(xi[cc] - rxB, 0), rwB - 1);
        tfB[r * 3 + cc] = ry_ * rwB + rx_;
        wB[r * 3 + cc] = yw[r] * xw[cc];
      }
  }

  float* po = out + ((size_t)(n * C + gb)) * HW + (size_t)y * W + x;

  if (l0 >= 1) {
    int offA, szA, rwA, rxA, ryA, SA;
    meta(l0, offA, szA, rwA, rxA, ryA, SA);
    int tfA[9]; float wA[9];
    {
      int xi[3]; float xw[3]; axis3(x0, x1, wx, l0, SA, xi, xw);
      int yi[3]; float yw[3]; axis3(y0, y1, wy, l0, SA, yi, yw);
#pragma unroll
      for (int r = 0; r < 3; r++)
#pragma unroll
        for (int cc = 0; cc < 3; cc++) {
          int ry_ = min(max(yi[r] - ryA, 0), rwA - 1);
          int rx_ = min(max(xi[cc] - rxA, 0), rwA - 1);
          tfA[r * 3 + cc] = ry_ * rwA + rx_;
          wA[r * 3 + cc] = yw[r] * xw[cc];
        }
    }
#pragma unroll
    for (int q = 0; q < 8; q++) {
      const float* pA = lds + offA + q * szA * 4;
      const float* pB = lds + offB + q * szB * 4;
      v4 accA = {0.f, 0.f, 0.f, 0.f};
      v4 accB = {0.f, 0.f, 0.f, 0.f};
#pragma unroll
      for (int t = 0; t < 9; t++)
        accA += *reinterpret_cast<const v4*>(pA + tfA[t] * 4) * wA[t];
#pragma unroll
      for (int t = 0; t < 9; t++)
        accB += *reinterpret_cast<const v4*>(pB + tfB[t] * 4) * wB[t];
      v4 o = accA + (accB - accA) * wl;
      float* pq = po + (size_t)(4 * q) * HW;
      pq[0] = o.x; pq[HW] = o.y; pq[2 * (size_t)HW] = o.z; pq[3 * (size_t)HW] = o.w;
    }
  } else {
    // rare path: level-0 == exact bilinear on inputs (global), B from LDS
    const float* inA = inputs + ((size_t)(n * C + gb)) * HW;
#pragma unroll 1
    for (int q = 0; q < 8; q++) {
      const float* pB = lds + offB + q * szB * 4;
      v4 accB = {0.f, 0.f, 0.f, 0.f};
#pragma unroll
      for (int t = 0; t < 9; t++)
        accB += *reinterpret_cast<const v4*>(pB + tfB[t] * 4) * wB[t];
      float av[4];
#pragma unroll
      for (int j = 0; j < 4; j++) {
        const float* ip = inA + (size_t)(4 * q + j) * HW;
        float v00 = ip[y0 * W + x0], v01 = ip[y0 * W + x1];
        float v10 = ip[y1 * W + x0], v11 = ip[y1 * W + x1];
        av[j] = (v00 * (1.f - wx) + v01 * wx) * (1.f - wy) +
                (v10 * (1.f - wx) + v11 * wx) * wy;
      }
      v4 accA = {av[0], av[1], av[2], av[3]};
      v4 o = accA + (accB - accA) * wl;
      float* pq = po + (size_t)(4 * q) * HW;
      pq[0] = o.x; pq[HW] = o.y; pq[2 * (size_t)HW] = o.z; pq[3 * (size_t)HW] = o.w;
    }
  }
}

}  // namespace

extern "C" void kernel_launch(void* const* d_in, const int* in_sizes, int n_in,
                              void* d_out, int out_size, void* d_ws, size_t ws_size,
                              hipStream_t stream) {
  const float* inputs = (const float*)d_in[0];
  const float* grid = (const float*)d_in[1];
  float* out = (float*)d_out;
  float* ws = (float*)d_ws;

  float* levels = ws;                                // N*H*W
  float* pyr1 = levels + (size_t)N * HW;             // N*C*128*128
  float* pyr2 = pyr1 + (size_t)N * C * 128 * 128;    // N*C*64*64
  float* pyr3 = pyr2 + (size_t)N * C * 64 * 64;      // N*C*32*32

  int tpix = N * HW;
  levels_kernel<<<tpix / 256, 256, 0, stream>>>(grid, levels);

  int NC = N * C;
  downsample_tiled<<<dim3(16, NC), 256, 0, stream>>>(inputs, pyr1, 256, 4);
  downsample_tiled<<<dim3(4, NC), 256, 0, stream>>>(pyr1, pyr2, 128, 2);
  downsample_tiled<<<dim3(1, NC), 256, 0, stream>>>(pyr2, pyr3, 64, 1);

  gather_tiled<<<dim3(256, 3, N), 256, 0, stream>>>(inputs, grid, levels,
                                                    pyr1, pyr2, pyr3, out);
}

// Round 6
// 256.175 us; speedup vs baseline: 2.2836x; 1.0137x over previous
//
#include <hip/hip_runtime.h>
#include <math.h>

namespace {

constexpr int N = 4, C = 96, H = 256, W = 256;
constexpr int HW = H * W;
constexpr float LMAX = 2.5f;

typedef float v4 __attribute__((ext_vector_type(4)));
struct __attribute__((packed, aligned(4))) V4U { v4 v; };
__device__ inline v4 load4u(const float* p) {
  return reinterpret_cast<const V4U*>(p)->v;
}
__device__ inline int refl(int i, int S) {
  i = i < 0 ? -i : i;
  return i >= S ? 2 * S - 2 - i : i;
}

// ------------------------------------------------------------ downsample1 ---
// input 256 -> pyr1 128. 32x32 output tile; stage 68x68 (reflect at edges),
// interior 4-col chunks via unaligned dwordx4.
__global__ __launch_bounds__(256) void downsample1(
    const float* __restrict__ in, float* __restrict__ out) {
  __shared__ float s[68 * 68];
  const int Wi = 256, Wo = 128, T = 4;
  int tile = blockIdx.x, nc = blockIdx.y;
  int tx0 = (tile % T) * 32, ty0 = (tile / T) * 32;
  int ix0 = 2 * tx0 - 2, iy0 = 2 * ty0 - 2;
  const float* p = in + (size_t)nc * Wi * Wi;
  int tid = threadIdx.x;

  for (int k = 0; k < 5; k++) {
    int ch = tid + 256 * k;
    if (ch < 68 * 17) {
      int yy = ch / 17, cx = (ch - 17 * yy) * 4;
      int gy = refl(iy0 + yy, Wi);
      int gx = ix0 + cx;
      const float* rowp = p + (size_t)gy * Wi;
      float* sp = s + yy * 68 + cx;
      if (gx >= 0 && gx + 3 < Wi) {
        v4 t = load4u(rowp + gx);
        sp[0] = t.x; sp[1] = t.y; sp[2] = t.z; sp[3] = t.w;
      } else {
#pragma unroll
        for (int j = 0; j < 4; j++) sp[j] = rowp[refl(gx + j, Wi)];
      }
    }
  }
  __syncthreads();

  const float fw[4] = {0.125f, 0.375f, 0.375f, 0.125f};
  int dx = tid & 31, dy0 = tid >> 5;
  float* po = out + (size_t)nc * Wo * Wo;
#pragma unroll
  for (int r = 0; r < 4; r++) {
    int dy = dy0 + 8 * r;
    float acc = 0.0f;
#pragma unroll
    for (int a = 0; a < 4; a++) {
      const float* row = s + (2 * dy + 1 + a) * 68 + 2 * dx + 1;
      acc = fmaf(fw[a],
                 fmaf(fw[0], row[0],
                 fmaf(fw[1], row[1],
                 fmaf(fw[2], row[2], fw[3] * row[3]))), acc);
    }
    po[(size_t)(ty0 + dy) * Wo + tx0 + dx] = acc;
  }
}

// ----------------------------------------------------------- downsample23 ---
// pyr1(128) -> pyr2(64) + pyr3(32), halo-chained in LDS. Per block: one 16x16
// pyr3 tile; pyr2 region [2t-1, 2t+32] (34), pyr1 region [4t-3, 4t+66] (70).
// Reflect at each level via index mapping (stays inside staged region).
__global__ __launch_bounds__(256) void downsample23(
    const float* __restrict__ pyr1, float* __restrict__ pyr2,
    float* __restrict__ pyr3) {
  __shared__ float s1[70 * 72];
  __shared__ float h2[70 * 36];
  __shared__ float p2[34 * 36];
  __shared__ float h3[34 * 16];
  int t = blockIdx.x, nc = blockIdx.y;
  int t3x = (t & 1) * 16, t3y = (t >> 1) * 16;
  int u0x = 2 * t3x - 1, u0y = 2 * t3y - 1;     // pyr2 region origin
  int v0x = 2 * u0x - 1, v0y = 2 * u0y - 1;     // pyr1 region origin
  const float* p1 = pyr1 + (size_t)nc * 128 * 128;
  int tid = threadIdx.x;
  const float fw[4] = {0.125f, 0.375f, 0.375f, 0.125f};

  // stage pyr1 region 70x70 (values reflect-mapped)
  for (int k = 0; k < 20; k++) {
    int e = tid + 256 * k;
    if (e < 4900) {
      int yy = e / 70, xx = e - 70 * yy;
      s1[yy * 72 + xx] =
          p1[(size_t)refl(v0y + yy, 128) * 128 + refl(v0x + xx, 128)];
    }
  }
  __syncthreads();

  // h2: horizontal ds of s1 -> 70 rows x 34 cols (rel col = 2c+k, in-region)
  for (int k = 0; k < 10; k++) {
    int e = tid + 256 * k;
    if (e < 70 * 34) {
      int r = e / 34, c = e - 34 * r;
      const float* sp = s1 + r * 72 + 2 * c;
      h2[r * 36 + c] = fmaf(fw[0], sp[0],
                       fmaf(fw[1], sp[1],
                       fmaf(fw[2], sp[2], fw[3] * sp[3])));
    }
  }
  __syncthreads();

  // p2: vertical ds -> 34x34 (rel row = 2r+k)
  for (int k = 0; k < 5; k++) {
    int e = tid + 256 * k;
    if (e < 34 * 34) {
      int r = e / 34, c = e - 34 * r;
      const float* hp = h2 + (2 * r) * 36 + c;
      p2[r * 36 + c] = fmaf(fw[0], hp[0],
                       fmaf(fw[1], hp[36],
                       fmaf(fw[2], hp[72], fw[3] * hp[108])));
    }
  }
  __syncthreads();

  // write pyr2 interior 32x32: abs = 2*t3 + [0,32), rel = abs - u0 = 1 + [0,32)
  float* o2 = pyr2 + (size_t)nc * 64 * 64;
#pragma unroll
  for (int k = 0; k < 4; k++) {
    int e = tid + 256 * k;
    int yy = e >> 5, xx = e & 31;
    o2[(size_t)(2 * t3y + yy) * 64 + 2 * t3x + xx] = p2[(yy + 1) * 36 + xx + 1];
  }

  // h3: horizontal ds of p2 region -> 34 rows x 16 cols (reflect at pyr2 lvl)
  for (int k = 0; k < 3; k++) {
    int e = tid + 256 * k;
    if (e < 34 * 16) {
      int r = e >> 4, c = e & 15;
      float acc = 0.f;
#pragma unroll
      for (int kk = 0; kk < 4; kk++) {
        int j = refl(2 * (t3x + c) - 1 + kk, 64) - u0x;  // in [0,34)
        acc = fmaf(fw[kk], p2[r * 36 + j], acc);
      }
      h3[r * 16 + c] = acc;
    }
  }
  __syncthreads();

  // p3: vertical ds -> 16x16 tile, write
  {
    int yy = tid >> 4, xx = tid & 15;
    float acc = 0.f;
#pragma unroll
    for (int kk = 0; kk < 4; kk++) {
      int j = refl(2 * (t3y + yy) - 1 + kk, 64) - u0y;  // in [0,34)
      acc = fmaf(fw[kk], h3[j * 16 + xx], acc);
    }
    pyr3[(size_t)nc * 32 * 32 + (t3y + yy) * 32 + t3x + xx] = acc;
  }
}

// ---------------------------------------------------------------- gather ----
__device__ inline void axis3(int q0, int q1, float wq, int l, int S,
                             int* ii, float* ww) {
  float inv = 1.0f / (float)(1 << l);
  float pos0 = ((float)q0 + 0.5f) * inv - 0.5f;
  float pos1 = ((float)q1 + 0.5f) * inv - 0.5f;
  int p0 = (int)floorf(pos0), p1 = (int)floorf(pos1);
  float f0 = pos0 - (float)p0, f1 = pos1 - (float)p1;
  int a0 = min(max(p0, 0), S - 1), a1 = min(max(p0 + 1, 0), S - 1);
  int b0 = min(max(p1, 0), S - 1), b1 = min(max(p1 + 1, 0), S - 1);
  int base = min(a0, b0);
  float w0 = 0.f, w1 = 0.f, w2 = 0.f;
  float v; int s;
  v = (1.0f - wq) * (1.0f - f0); s = a0 - base;
  w0 += (s == 0) ? v : 0.f; w1 += (s == 1) ? v : 0.f; w2 += (s == 2) ? v : 0.f;
  v = (1.0f - wq) * f0;          s = a1 - base;
  w0 += (s == 0) ? v : 0.f; w1 += (s == 1) ? v : 0.f; w2 += (s == 2) ? v : 0.f;
  v = wq * (1.0f - f1);          s = b0 - base;
  w0 += (s == 0) ? v : 0.f; w1 += (s == 1) ? v : 0.f; w2 += (s == 2) ? v : 0.f;
  v = wq * f1;                   s = b1 - base;
  w0 += (s == 0) ? v : 0.f; w1 += (s == 1) ? v : 0.f; w2 += (s == 2) ? v : 0.f;
  ii[0] = base;
  ii[1] = min(base + 1, S - 1);
  ii[2] = min(base + 2, S - 1);
  ww[0] = w0; ww[1] = w1; ww[2] = w2;
}

// LDS: quad-planar per level: dword = OFF + q*SZ*4 + tf*4 + j  (c = 4q+j)
constexpr int L2OFF = 8192, L3OFF = 11392, LDSTOT = 12544;

__global__ __launch_bounds__(256, 3) void gather_tiled(
    const float* __restrict__ inputs, const float* __restrict__ grid,
    const float* __restrict__ pyr1, const float* __restrict__ pyr2,
    const float* __restrict__ pyr3, float* __restrict__ out) {
  __shared__ __align__(16) float lds[LDSTOT];
  int tile = blockIdx.x, g = blockIdx.y, n = blockIdx.z;
  int tx0 = (tile & 15) << 4, ty0 = (tile >> 4) << 4;
  int gb = g * 32;
  int tid = threadIdx.x;

  int px = tid & 15, py = tid >> 4;
  int x = tx0 + px, y = ty0 + py;

  // early grid loads for sampling + inline levels (overlap with staging)
  const float2* gp = reinterpret_cast<const float2*>(grid) + (size_t)n * HW;
  float2 gc = gp[y * W + x];
  float2 gl = gp[y * W + max(x - 1, 0)];
  float2 gr = gp[y * W + min(x + 1, W - 1)];
  float2 gu = gp[max(y - 1, 0) * W + x];
  float2 gd = gp[min(y + 1, H - 1) * W + x];

  // staged-region origins
  int rsx1 = min(max((tx0 >> 1) - 4, 0), 128 - 16);
  int rsy1 = min(max((ty0 >> 1) - 4, 0), 128 - 16);
  int rsx2 = min(max((tx0 >> 2) - 3, 0), 64 - 10);
  int rsy2 = min(max((ty0 >> 2) - 3, 0), 64 - 10);
  int rsx3 = min(max((tx0 >> 3) - 2, 0), 32 - 6);
  int rsy3 = min(max((ty0 >> 3) - 2, 0), 32 - 6);

  // ---- stage L1: 32ch x 256 taps ----
  {
    const float* base = pyr1 + ((size_t)(n * C + gb)) * (128 * 128);
#pragma unroll
    for (int k = 0; k < 32; k++) {
      int e = tid + 256 * k;
      int c = e >> 8, tf = e & 255;
      int yy = tf >> 4, xx = tf & 15;
      float t = base[(size_t)c * (128 * 128) + (rsy1 + yy) * 128 + rsx1 + xx];
      lds[(c >> 2) * 1024 + tf * 4 + (c & 3)] = t;
    }
  }
  // ---- stage L2: 32ch x 100 taps ----
  {
    const float* base = pyr2 + ((size_t)(n * C + gb)) * (64 * 64);
    for (int k = 0; k < 13; k++) {
      int e = tid + 256 * k;
      if (e < 3200) {
        int c = e / 100, tf = e - 100 * c;
        int yy = tf / 10, xx = tf - 10 * yy;
        float t = base[(size_t)c * (64 * 64) + (rsy2 + yy) * 64 + rsx2 + xx];
        lds[L2OFF + (c >> 2) * 400 + tf * 4 + (c & 3)] = t;
      }
    }
  }
  // ---- stage L3: 32ch x 36 taps ----
  {
    const float* base = pyr3 + ((size_t)(n * C + gb)) * (32 * 32);
    for (int k = 0; k < 5; k++) {
      int e = tid + 256 * k;
      if (e < 1152) {
        int c = e / 36, tf = e - 36 * c;
        int yy = tf / 6, xx = tf - 6 * yy;
        float t = base[(size_t)c * (32 * 32) + (rsy3 + yy) * 32 + rsx3 + xx];
        lds[L3OFF + (c >> 2) * 144 + tf * 4 + (c & 3)] = t;
      }
    }
  }
  __syncthreads();

  // ---- inline levels (same math as the old levels_kernel) ----
  float lv;
  {
    float cx = 255.0f * (gc.x + 1.0f) * 0.5f;
    float cy = 255.0f * (gc.y + 1.0f) * 0.5f;
    float m = 1.0f;
    float2 nb[4] = {gl, gr, gu, gd};
#pragma unroll
    for (int i = 0; i < 4; i++) {
      float ox = 255.0f * (nb[i].x + 1.0f) * 0.5f - cx;
      float oy = 255.0f * (nb[i].y + 1.0f) * 0.5f - cy;
      m = fmaxf(m, ox * ox + oy * oy);
    }
    lv = fminf(fmaxf(0.5f * __log2f(m), 0.0f), LMAX);
  }

  // sampling coords (grid_sample border, align_corners=False)
  float ix = fminf(fmaxf(fmaf(gc.x + 1.0f, 128.0f, -0.5f), 0.0f), 255.0f);
  float iy = fminf(fmaxf(fmaf(gc.y + 1.0f, 128.0f, -0.5f), 0.0f), 255.0f);
  int x0 = (int)floorf(ix); float wx = ix - (float)x0; int x1 = min(x0 + 1, 255);
  int y0 = (int)floorf(iy); float wy = iy - (float)y0; int y1 = min(y0 + 1, 255);

  float lf = floorf(lv);
  int l0 = (int)lf;
  float wl = lv - lf;
  float wlA = 1.0f - wl;
  int lB = l0 + 1;  // in [1,3]

  auto meta = [&](int l, int& off, int& sz, int& rw, int& rx, int& ry, int& S) {
    if (l == 1)      { off = 0;     sz = 256; rw = 16; rx = rsx1; ry = rsy1; S = 128; }
    else if (l == 2) { off = L2OFF; sz = 100; rw = 10; rx = rsx2; ry = rsy2; S = 64; }
    else             { off = L3OFF; sz = 36;  rw = 6;  rx = rsx3; ry = rsy3; S = 32; }
  };

  // B-level taps, pre-scaled by wl
  int offB, szB, rwB, rxB, ryB, SB;
  meta(lB, offB, szB, rwB, rxB, ryB, SB);
  int tfB[9]; float wB[9];
  {
    int xi[3]; float xw[3]; axis3(x0, x1, wx, lB, SB, xi, xw);
    int yi[3]; float yw[3]; axis3(y0, y1, wy, lB, SB, yi, yw);
#pragma unroll
    for (int r = 0; r < 3; r++)
#pragma unroll
      for (int cc = 0; cc < 3; cc++) {
        int ry_ = min(max(yi[r] - ryB, 0), rwB - 1);
        int rx_ = min(max(xi[cc] - rxB, 0), rwB - 1);
        tfB[r * 3 + cc] = ry_ * rwB + rx_;
        wB[r * 3 + cc] = yw[r] * xw[cc] * wl;
      }
  }

  float* po = out + ((size_t)(n * C + gb)) * HW + (size_t)y * W + x;

  if (l0 >= 1) {
    int offA, szA, rwA, rxA, ryA, SA;
    meta(l0, offA, szA, rwA, rxA, ryA, SA);
    int tfA[9]; float wA[9];
    {
      int xi[3]; float xw[3]; axis3(x0, x1, wx, l0, SA, xi, xw);
      int yi[3]; float yw[3]; axis3(y0, y1, wy, l0, SA, yi, yw);
#pragma unroll
      for (int r = 0; r < 3; r++)
#pragma unroll
        for (int cc = 0; cc < 3; cc++) {
          int ry_ = min(max(yi[r] - ryA, 0), rwA - 1);
          int rx_ = min(max(xi[cc] - rxA, 0), rwA - 1);
          tfA[r * 3 + cc] = ry_ * rwA + rx_;
          wA[r * 3 + cc] = yw[r] * xw[cc] * wlA;
        }
    }
#pragma unroll
    for (int q = 0; q < 8; q++) {
      const float* pA = lds + offA + q * szA * 4;
      const float* pB = lds + offB + q * szB * 4;
      v4 acc = {0.f, 0.f, 0.f, 0.f};
#pragma unroll
      for (int t = 0; t < 9; t++)
        acc += *reinterpret_cast<const v4*>(pA + tfA[t] * 4) * wA[t];
#pragma unroll
      for (int t = 0; t < 9; t++)
        acc += *reinterpret_cast<const v4*>(pB + tfB[t] * 4) * wB[t];
      float* pq = po + (size_t)(4 * q) * HW;
      pq[0] = acc.x; pq[HW] = acc.y;
      pq[2 * (size_t)HW] = acc.z; pq[3 * (size_t)HW] = acc.w;
    }
  } else {
    // rare path: level-0 == exact bilinear on inputs (global), B from LDS
    const float* inA = inputs + ((size_t)(n * C + gb)) * HW;
#pragma unroll 1
    for (int q = 0; q < 8; q++) {
      const float* pB = lds + offB + q * szB * 4;
      v4 accB = {0.f, 0.f, 0.f, 0.f};
#pragma unroll
      for (int t = 0; t < 9; t++)
        accB += *reinterpret_cast<const v4*>(pB + tfB[t] * 4) * wB[t];
      float av[4];
#pragma unroll
      for (int j = 0; j < 4; j++) {
        const float* ip = inA + (size_t)(4 * q + j) * HW;
        float v00 = ip[y0 * W + x0], v01 = ip[y0 * W + x1];
        float v10 = ip[y1 * W + x0], v11 = ip[y1 * W + x1];
        av[j] = (v00 * (1.f - wx) + v01 * wx) * (1.f - wy) +
                (v10 * (1.f - wx) + v11 * wx) * wy;
      }
      v4 o = {fmaf(av[0], wlA, accB.x), fmaf(av[1], wlA, accB.y),
              fmaf(av[2], wlA, accB.z), fmaf(av[3], wlA, accB.w)};
      float* pq = po + (size_t)(4 * q) * HW;
      pq[0] = o.x; pq[HW] = o.y;
      pq[2 * (size_t)HW] = o.z; pq[3 * (size_t)HW] = o.w;
    }
  }
}

}  // namespace

extern "C" void kernel_launch(void* const* d_in, const int* in_sizes, int n_in,
                              void* d_out, int out_size, void* d_ws, size_t ws_size,
                              hipStream_t stream) {
  const float* inputs = (const float*)d_in[0];
  const float* grid = (const float*)d_in[1];
  float* out = (float*)d_out;
  float* ws = (float*)d_ws;

  float* pyr1 = ws;                                  // N*C*128*128 = 25.2 MB
  float* pyr2 = pyr1 + (size_t)N * C * 128 * 128;    // N*C*64*64   =  6.3 MB
  float* pyr3 = pyr2 + (size_t)N * C * 64 * 64;      // N*C*32*32   =  1.6 MB

  int NC = N * C;
  downsample1<<<dim3(16, NC), 256, 0, stream>>>(inputs, pyr1);
  downsample23<<<dim3(4, NC), 256, 0, stream>>>(pyr1, pyr2, pyr3);
  gather_tiled<<<dim3(256, 3, N), 256, 0, stream>>>(inputs, grid,
                                                    pyr1, pyr2, pyr3, out);
}